// Round 6
// baseline (549.122 us; speedup 1.0000x reference)
//
#include <hip/hip_runtime.h>
#include <math.h>

// B=16, H=64, W=64, C=256; M=65536 pixels. Inputs fp32 (runtime-detected),
// canonicalized to bf16. Compute: bf16 MFMA 16x16x32, fp32 accum.
// R6: GEMM BK=64 (halved barrier drains) + XOR-swizzled LDS (2-way banks,
// free) via global_load_lds lane->global-chunk permutation; perc fused with
// h->bf16 conversion (conv_h removed); attn 8ch/lane (2 px/wave).

typedef unsigned short u16;
typedef __bf16 bf16x8 __attribute__((ext_vector_type(8)));
typedef float floatx4 __attribute__((ext_vector_type(4)));

__device__ int g_flag;  // 0 = bf16 inputs, 1 = fp32 inputs
__device__ __align__(16) u16 g_h[16777216];     // canonical bf16 h  [65536,256]
__device__ __align__(16) u16 g_perc[50331648];  // perceived/qkv     [65536,768]
__device__ __align__(16) u16 g_hid[33554432];   // hid               [65536,512]
__device__ __align__(16) u16 g_hnew[16777216];  // h_new             [65536,256]
__device__ __align__(16) u16 g_wperc[6912];
__device__ __align__(16) u16 g_bperc[768];
__device__ __align__(16) u16 g_wup1[393216];
__device__ __align__(16) u16 g_bup1[512];
__device__ __align__(16) u16 g_wup2[131072];
__device__ __align__(16) u16 g_bup2[256];
__device__ __align__(16) u16 g_wqkv[196608];
__device__ __align__(16) u16 g_bqkv[768];

__device__ __forceinline__ float b2f(u16 x) {
  unsigned int u = ((unsigned int)x) << 16;
  float f;
  __builtin_memcpy(&f, &u, 4);
  return f;
}
__device__ __forceinline__ u16 f2b(float f) {
  unsigned int u;
  __builtin_memcpy(&u, &f, 4);
  u += 0x7FFFu + ((u >> 16) & 1u);  // round-to-nearest-even
  return (u16)(u >> 16);
}
// async global->LDS, 16B per lane; LDS dest = wave-uniform base + lane*16.
__device__ __forceinline__ void gload16(const u16* g, u16* l) {
  __builtin_amdgcn_global_load_lds(
      (const __attribute__((address_space(1))) unsigned int*)g,
      (__attribute__((address_space(3))) unsigned int*)l, 16, 0, 0);
}
__device__ __forceinline__ void ld8(const u16* p, float* f) {
  uint4 v = *(const uint4*)p;
  f[0] = b2f((u16)(v.x & 0xFFFF)); f[1] = b2f((u16)(v.x >> 16));
  f[2] = b2f((u16)(v.y & 0xFFFF)); f[3] = b2f((u16)(v.y >> 16));
  f[4] = b2f((u16)(v.z & 0xFFFF)); f[5] = b2f((u16)(v.z >> 16));
  f[6] = b2f((u16)(v.w & 0xFFFF)); f[7] = b2f((u16)(v.w >> 16));
}

// --------------------------------------------------------------------------
// dtype probe: even u16 halves of fp32 data hit exp==0xFF w.p. 1/256;
// bf16 N(0,1) data never does.
// --------------------------------------------------------------------------
__global__ __launch_bounds__(256) void probe_kernel(const u16* __restrict__ h) {
  __shared__ int hit;
  if (threadIdx.x == 0) hit = 0;
  __syncthreads();
  int local = 0;
  for (int i = threadIdx.x; i < 8192; i += 256) {
    u16 v = h[2 * i];
    if ((v & 0x7F80) == 0x7F80) local = 1;
  }
  if (local) atomicOr(&hit, 1);
  __syncthreads();
  if (threadIdx.x == 0) g_flag = hit;
}

// canonicalize all 8 weight/bias tensors in one launch
__global__ __launch_bounds__(256) void conv_w_kernel(
    const void* i1, const void* i2, const void* i3, const void* i4,
    const void* i5, const void* i6, const void* i7, const void* i8) {
  const void* srcs[8] = {i1, i2, i3, i4, i5, i6, i7, i8};
  u16* dsts[8] = {g_wperc, g_bperc, g_wup1, g_bup1,
                  g_wup2,  g_bup2,  g_wqkv, g_bqkv};
  const int szs[8] = {6912, 768, 393216, 512, 131072, 256, 196608, 768};
  const int fp32 = g_flag;
  const int stride = gridDim.x * 256;
  for (int gw = blockIdx.x * 256 + threadIdx.x; gw < 730112; gw += stride) {
    int seg = 0, off = gw;
    while (off >= szs[seg]) { off -= szs[seg]; ++seg; }
    dsts[seg][off] = fp32 ? f2b(((const float*)srcs[seg])[off])
                          : ((const u16*)srcs[seg])[off];
  }
}

// --------------------------------------------------------------------------
// grouped 3x3 perception conv fused with h->bf16 canonicalization.
// Block=(b,y) row; wave=16-px x-strip, lane=4-channel group. Sliding 3-col
// register window. Reads raw h (fp32 or bf16 per g_flag); writes g_h (bf16)
// and g_perc [pix][768] (d=3c+t group-major).
// --------------------------------------------------------------------------
__global__ __launch_bounds__(256) void perc_kernel(const void* __restrict__ hin) {
  __shared__ __align__(16) u16 sw[6912];
  __shared__ __align__(16) u16 sb[768];
  const int bid = blockIdx.x;  // b*64 + y
  const int b = bid >> 6, y = bid & 63;
  const int xi = threadIdx.x >> 6;  // wave id: x-strip
  const int cg = threadIdx.x & 63;  // channel group (4 ch)
  const int c0 = cg * 4;
  for (int i = threadIdx.x; i < 6912; i += 256) sw[i] = g_wperc[i];
  for (int i = threadIdx.x; i < 768; i += 256) sb[i] = g_bperc[i];
  const int fp32 = g_flag;
  __syncthreads();
  float w[4][27], bias[4][3];
#pragma unroll
  for (int ch = 0; ch < 4; ++ch) {
#pragma unroll
    for (int t = 0; t < 3; ++t) {
      bias[ch][t] = b2f(sb[3 * (c0 + ch) + t]);
#pragma unroll
      for (int j = 0; j < 9; ++j)
        w[ch][t * 9 + j] = b2f(sw[(3 * (c0 + ch) + t) * 9 + j]);
    }
  }
  float hv[3][3][4];  // [row][colslot][ch]
  auto loadcol = [&](int xx, int cc) {
#pragma unroll
    for (int r = 0; r < 3; ++r) {
      const int yy = y - 1 + r;
      const bool ok = ((unsigned)yy < 64u) && ((unsigned)xx < 64u);
      if (ok) {
        const size_t idx = (((size_t)(b * 64 + yy) * 64) + xx) * 256 + c0;
        if (fp32) {
          const float4 v = *(const float4*)((const float*)hin + idx);
          hv[r][cc][0] = v.x; hv[r][cc][1] = v.y;
          hv[r][cc][2] = v.z; hv[r][cc][3] = v.w;
        } else {
          const uint2 v = *(const uint2*)((const u16*)hin + idx);
          hv[r][cc][0] = b2f((u16)(v.x & 0xFFFF));
          hv[r][cc][1] = b2f((u16)(v.x >> 16));
          hv[r][cc][2] = b2f((u16)(v.y & 0xFFFF));
          hv[r][cc][3] = b2f((u16)(v.y >> 16));
        }
      } else {
        hv[r][cc][0] = 0.0f; hv[r][cc][1] = 0.0f;
        hv[r][cc][2] = 0.0f; hv[r][cc][3] = 0.0f;
      }
    }
  };
  const int x0 = xi * 16;
  loadcol(x0 - 1, 0);
  loadcol(x0, 1);
#pragma unroll 4
  for (int k = 0; k < 16; ++k) {
    const int x = x0 + k;
    loadcol(x + 1, (k + 2) % 3);
    const int cL = k % 3, cM = (k + 1) % 3, cR = (k + 2) % 3;
    const size_t pix = (size_t)(b * 64 + y) * 64 + x;
    // emit canonical bf16 h (center row/col round-trips exactly for bf16 in)
    uint2 hc;
    hc.x = (unsigned)f2b(hv[1][cM][0]) | ((unsigned)f2b(hv[1][cM][1]) << 16);
    hc.y = (unsigned)f2b(hv[1][cM][2]) | ((unsigned)f2b(hv[1][cM][3]) << 16);
    *(uint2*)&g_h[pix * 256 + c0] = hc;
    u16* op = &g_perc[pix * 768 + 3 * c0];
    unsigned pk[6];
#pragma unroll
    for (int ch = 0; ch < 4; ++ch) {
#pragma unroll
      for (int t = 0; t < 3; ++t) {
        const float* wt = &w[ch][t * 9];
        float a = bias[ch][t];
        a += hv[0][cL][ch] * wt[0] + hv[0][cM][ch] * wt[1] + hv[0][cR][ch] * wt[2];
        a += hv[1][cL][ch] * wt[3] + hv[1][cM][ch] * wt[4] + hv[1][cR][ch] * wt[5];
        a += hv[2][cL][ch] * wt[6] + hv[2][cM][ch] * wt[7] + hv[2][cR][ch] * wt[8];
        const int o = 3 * ch + t;
        const unsigned bb = f2b(a);
        if (o & 1) pk[o >> 1] |= bb << 16; else pk[o >> 1] = bb;
      }
    }
    uint2 r0; r0.x = pk[0]; r0.y = pk[1];
    uint2 r1; r1.x = pk[2]; r1.y = pk[3];
    uint2 r2; r2.x = pk[4]; r2.y = pk[5];
    *(uint2*)(op) = r0;
    *(uint2*)(op + 4) = r1;
    *(uint2*)(op + 8) = r2;
  }
}

// --------------------------------------------------------------------------
// MFMA bf16 GEMM: C[M,N] = epi(A[M,K] * W[N,K]^T + bias[N])
// BM=BN=128, BK=64 (12/8/4 iters), 4 waves 2x2, 4x4 mfma_f32_16x16x32_bf16.
// global_load_lds(16B) staging into XOR-swizzled LDS: 16B slot s holds
// global chunk ((s>>3), (s&7)^((s>>3)&7)) -> ds_read_b128 aliasing is 2-way
// (free, m136). XCD swizzle: bid&7 picks M-slab (A shared within an XCD L2).
// MODE 0: perceived@wup1 +GELU -> hid.  MODE 1: hid@wup2 +h -> hnew.
// MODE 2: hnew@wqkv -> qkv (g_perc reuse).
// --------------------------------------------------------------------------
template <int MODE, int NB>
__global__ __launch_bounds__(256) void gemm_bt(int K) {
  const u16 *A, *Bw, *bias, *resid;
  u16* C;
  if (MODE == 0) { A = g_perc; Bw = g_wup1; bias = g_bup1; resid = nullptr; C = g_hid; }
  if (MODE == 1) { A = g_hid;  Bw = g_wup2; bias = g_bup2; resid = g_h;     C = g_hnew; }
  if (MODE == 2) { A = g_hnew; Bw = g_wqkv; bias = g_bqkv; resid = nullptr; C = g_perc; }
  const int N = NB * 128;

  __shared__ __align__(16) u16 Al[128 * 64];
  __shared__ __align__(16) u16 Bl[128 * 64];
  const int tid = threadIdx.x;
  const int wave = tid >> 6, lane = tid & 63;
  const int ln = lane & 15, quad = lane >> 4;
  const int lnx = ln & 7;
  const int mb_per_xcd = (gridDim.x / NB) >> 3;
  const int m_blk = (blockIdx.x & 7) * mb_per_xcd + (blockIdx.x >> 3) / NB;
  const int n_blk = (blockIdx.x >> 3) % NB;
  const int m0 = m_blk * 128, n0 = n_blk * 128;
  const int wm = (wave >> 1) * 64, wn = (wave & 1) * 64;
  floatx4 acc[4][4] = {};

  // staging geometry: 1024 slots of 16B per matrix; 4 rounds of 256.
  int srow[4], scol[4];
#pragma unroll
  for (int r = 0; r < 4; ++r) {
    const int slot = r * 256 + tid;
    srow[r] = slot >> 3;
    scol[r] = ((slot & 7) ^ (srow[r] & 7)) * 8;
  }

  for (int k0 = 0; k0 < K; k0 += 64) {
#pragma unroll
    for (int r = 0; r < 4; ++r)
      gload16(&A[(size_t)(m0 + srow[r]) * K + k0 + scol[r]],
              &Al[(r * 256 + tid) * 8]);
#pragma unroll
    for (int r = 0; r < 4; ++r)
      gload16(&Bw[(size_t)(n0 + srow[r]) * K + k0 + scol[r]],
              &Bl[(r * 256 + tid) * 8]);
    __syncthreads();
#pragma unroll
    for (int kk8 = 0; kk8 < 8; kk8 += 4) {
      bf16x8 af[4], bfr[4];
#pragma unroll
      for (int i = 0; i < 4; ++i) {
        const int row = wm + i * 16 + ln;
        af[i] = *(const bf16x8*)(&Al[(row * 8 + ((kk8 + quad) ^ lnx)) * 8]);
      }
#pragma unroll
      for (int j = 0; j < 4; ++j) {
        const int row = wn + j * 16 + ln;
        bfr[j] = *(const bf16x8*)(&Bl[(row * 8 + ((kk8 + quad) ^ lnx)) * 8]);
      }
#pragma unroll
      for (int i = 0; i < 4; ++i)
#pragma unroll
        for (int j = 0; j < 4; ++j)
          acc[i][j] = __builtin_amdgcn_mfma_f32_16x16x32_bf16(af[i], bfr[j],
                                                              acc[i][j], 0, 0, 0);
    }
    __syncthreads();
  }

#pragma unroll
  for (int i = 0; i < 4; ++i) {
#pragma unroll
    for (int rr = 0; rr < 4; ++rr) {
      const int m = m0 + wm + i * 16 + quad * 4 + rr;
#pragma unroll
      for (int j = 0; j < 4; ++j) {
        const int n = n0 + wn + j * 16 + ln;
        float v = acc[i][j][rr] + b2f(bias[n]);
        if (MODE == 0) v = 0.5f * v * (1.0f + erff(v * 0.70710678118654752f));
        if (MODE == 1) v += b2f(resid[(size_t)m * N + n]);
        C[(size_t)m * N + n] = f2b(v);
      }
    }
  }
}

// --------------------------------------------------------------------------
// 3x3 windowed local attention (zero-padded borders). Wave = 2 pixels
// (32 lanes each), lane = 8 channels (uint4 loads). OOB neighbor => score 0
// in softmax, zero value. out = hnew + attn, dtype per g_flag.
// --------------------------------------------------------------------------
__global__ __launch_bounds__(256) void attn_kernel(void* __restrict__ outv) {
  const int wv = threadIdx.x >> 6, lane = threadIdx.x & 63;
  const int half = lane >> 5, cl = lane & 31;
  const int c0 = cl * 8;
  const int pix = blockIdx.x * 8 + wv * 2 + half;
  const int y = (pix >> 6) & 63, x = pix & 63;
  float q[8];
  ld8(g_perc + (size_t)pix * 768 + c0, q);
  float s[9];
  int nidx[9];
#pragma unroll
  for (int j = 0; j < 9; ++j) {
    const int dy = j / 3 - 1, dx = j % 3 - 1;
    const int yy = y + dy, xx = x + dx;
    const bool ok = ((unsigned)yy < 64u) && ((unsigned)xx < 64u);
    const int np = pix + dy * 64 + dx;  // same image when ok
    nidx[j] = ok ? np : -1;
    float p = 0.0f;
    if (ok) {
      float kv[8];
      ld8(g_perc + (size_t)np * 768 + 256 + c0, kv);
      p = q[0] * kv[0] + q[1] * kv[1] + q[2] * kv[2] + q[3] * kv[3] +
          q[4] * kv[4] + q[5] * kv[5] + q[6] * kv[6] + q[7] * kv[7];
    }
#pragma unroll
    for (int off = 16; off >= 1; off >>= 1) p += __shfl_xor(p, off, 64);
    s[j] = p * 0.0625f;  // 1/sqrt(256)
  }
  float mx = s[0];
#pragma unroll
  for (int j = 1; j < 9; ++j) mx = fmaxf(mx, s[j]);
  float e[9], den = 0.0f;
#pragma unroll
  for (int j = 0; j < 9; ++j) {
    e[j] = expf(s[j] - mx);
    den += e[j];
  }
  const float inv = 1.0f / den;
  float a[8];
  ld8(g_hnew + (size_t)pix * 256 + c0, a);
#pragma unroll
  for (int j = 0; j < 9; ++j) {
    if (nidx[j] >= 0) {
      const float wgt = e[j] * inv;
      float vv[8];
      ld8(g_perc + (size_t)nidx[j] * 768 + 512 + c0, vv);
#pragma unroll
      for (int t = 0; t < 8; ++t) a[t] += wgt * vv[t];
    }
  }
  const size_t o = (size_t)pix * 256 + c0;
  if (g_flag) {
    float4 r0 = {a[0], a[1], a[2], a[3]};
    float4 r1 = {a[4], a[5], a[6], a[7]};
    *(float4*)((float*)outv + o) = r0;
    *(float4*)((float*)outv + o + 4) = r1;
  } else {
    uint4 r;
    r.x = (unsigned)f2b(a[0]) | ((unsigned)f2b(a[1]) << 16);
    r.y = (unsigned)f2b(a[2]) | ((unsigned)f2b(a[3]) << 16);
    r.z = (unsigned)f2b(a[4]) | ((unsigned)f2b(a[5]) << 16);
    r.w = (unsigned)f2b(a[6]) | ((unsigned)f2b(a[7]) << 16);
    *(uint4*)((u16*)outv + o) = r;
  }
}

// --------------------------------------------------------------------------
extern "C" void kernel_launch(void* const* d_in, const int* in_sizes, int n_in,
                              void* d_out, int d_out_size, void* d_ws,
                              size_t ws_size, hipStream_t stream) {
  (void)d_ws; (void)ws_size;
  probe_kernel<<<1, 256, 0, stream>>>((const u16*)d_in[0]);
  conv_w_kernel<<<360, 256, 0, stream>>>(d_in[1], d_in[2], d_in[3], d_in[4],
                                         d_in[5], d_in[6], d_in[7], d_in[8]);
  // perception + h canonicalization
  perc_kernel<<<1024, 256, 0, stream>>>(d_in[0]);
  // hid = GELU(perceived @ w_up1^T + b_up1)   [65536 x 512, K=768]
  gemm_bt<0, 4><<<2048, 256, 0, stream>>>(768);
  // h_new = h + hid @ w_up2^T + b_up2         [65536 x 256, K=512]
  gemm_bt<1, 2><<<1024, 256, 0, stream>>>(512);
  // qkv = h_new @ w_qkv^T + b_qkv             [65536 x 768, K=256]
  gemm_bt<2, 6><<<3072, 256, 0, stream>>>(256);
  // out = h_new + local_attn(qkv)
  attn_kernel<<<8192, 256, 0, stream>>>(d_out);
}

// Round 7
// 428.428 us; speedup vs baseline: 1.2817x; 1.2817x over previous
//
#include <hip/hip_runtime.h>
#include <math.h>

// B=16, H=64, W=64, C=256; M=65536 pixels. Inputs fp32 (runtime-detected),
// canonicalized to bf16. Compute: bf16 MFMA 16x16x32, fp32 accum.
// R7: perc fixed — FULL unroll (constant window indices -> hv in VGPRs; R6's
// partial unroll caused dynamic indexing -> scratch spills, 352MB writes) and
// 2 ch/lane (w[2][27]: ~95 VGPR, no spill). GEMM kept from R6 (BK=64 + XOR
// LDS swizzle) to get its measurement.

typedef unsigned short u16;
typedef __bf16 bf16x8 __attribute__((ext_vector_type(8)));
typedef float floatx4 __attribute__((ext_vector_type(4)));

__device__ int g_flag;  // 0 = bf16 inputs, 1 = fp32 inputs
__device__ __align__(16) u16 g_h[16777216];     // canonical bf16 h  [65536,256]
__device__ __align__(16) u16 g_perc[50331648];  // perceived/qkv     [65536,768]
__device__ __align__(16) u16 g_hid[33554432];   // hid               [65536,512]
__device__ __align__(16) u16 g_hnew[16777216];  // h_new             [65536,256]
__device__ __align__(16) u16 g_wperc[6912];
__device__ __align__(16) u16 g_bperc[768];
__device__ __align__(16) u16 g_wup1[393216];
__device__ __align__(16) u16 g_bup1[512];
__device__ __align__(16) u16 g_wup2[131072];
__device__ __align__(16) u16 g_bup2[256];
__device__ __align__(16) u16 g_wqkv[196608];
__device__ __align__(16) u16 g_bqkv[768];

__device__ __forceinline__ float b2f(u16 x) {
  unsigned int u = ((unsigned int)x) << 16;
  float f;
  __builtin_memcpy(&f, &u, 4);
  return f;
}
__device__ __forceinline__ u16 f2b(float f) {
  unsigned int u;
  __builtin_memcpy(&u, &f, 4);
  u += 0x7FFFu + ((u >> 16) & 1u);  // round-to-nearest-even
  return (u16)(u >> 16);
}
// async global->LDS, 16B per lane; LDS dest = wave-uniform base + lane*16.
__device__ __forceinline__ void gload16(const u16* g, u16* l) {
  __builtin_amdgcn_global_load_lds(
      (const __attribute__((address_space(1))) unsigned int*)g,
      (__attribute__((address_space(3))) unsigned int*)l, 16, 0, 0);
}
__device__ __forceinline__ void ld8(const u16* p, float* f) {
  uint4 v = *(const uint4*)p;
  f[0] = b2f((u16)(v.x & 0xFFFF)); f[1] = b2f((u16)(v.x >> 16));
  f[2] = b2f((u16)(v.y & 0xFFFF)); f[3] = b2f((u16)(v.y >> 16));
  f[4] = b2f((u16)(v.z & 0xFFFF)); f[5] = b2f((u16)(v.z >> 16));
  f[6] = b2f((u16)(v.w & 0xFFFF)); f[7] = b2f((u16)(v.w >> 16));
}

// --------------------------------------------------------------------------
// dtype probe: even u16 halves of fp32 data hit exp==0xFF w.p. 1/256;
// bf16 N(0,1) data never does.
// --------------------------------------------------------------------------
__global__ __launch_bounds__(256) void probe_kernel(const u16* __restrict__ h) {
  __shared__ int hit;
  if (threadIdx.x == 0) hit = 0;
  __syncthreads();
  int local = 0;
  for (int i = threadIdx.x; i < 8192; i += 256) {
    u16 v = h[2 * i];
    if ((v & 0x7F80) == 0x7F80) local = 1;
  }
  if (local) atomicOr(&hit, 1);
  __syncthreads();
  if (threadIdx.x == 0) g_flag = hit;
}

// canonicalize all 8 weight/bias tensors in one launch
__global__ __launch_bounds__(256) void conv_w_kernel(
    const void* i1, const void* i2, const void* i3, const void* i4,
    const void* i5, const void* i6, const void* i7, const void* i8) {
  const void* srcs[8] = {i1, i2, i3, i4, i5, i6, i7, i8};
  u16* dsts[8] = {g_wperc, g_bperc, g_wup1, g_bup1,
                  g_wup2,  g_bup2,  g_wqkv, g_bqkv};
  const int szs[8] = {6912, 768, 393216, 512, 131072, 256, 196608, 768};
  const int fp32 = g_flag;
  const int stride = gridDim.x * 256;
  for (int gw = blockIdx.x * 256 + threadIdx.x; gw < 730112; gw += stride) {
    int seg = 0, off = gw;
    while (off >= szs[seg]) { off -= szs[seg]; ++seg; }
    dsts[seg][off] = fp32 ? f2b(((const float*)srcs[seg])[off])
                          : ((const u16*)srcs[seg])[off];
  }
}

// --------------------------------------------------------------------------
// grouped 3x3 perception conv fused with h->bf16 canonicalization.
// grid 2048: blockIdx = (b*64+y)*2 + channel-half. Wave = 16-px x-strip,
// lane = 2-channel group (w[2][27] ~ 95 VGPR, no spill). FULL unroll so the
// sliding-window slot indices are compile-time constants (hv stays in VGPRs).
// Reads raw h (fp32/bf16 per g_flag); writes g_h (bf16) + g_perc [pix][768].
// --------------------------------------------------------------------------
__global__ __launch_bounds__(256) void perc_kernel(const void* __restrict__ hin) {
  __shared__ __align__(16) u16 sw[3456];
  __shared__ __align__(16) u16 sb[384];
  const int bid = blockIdx.x >> 1;  // b*64 + y
  const int chalf = blockIdx.x & 1;
  const int b = bid >> 6, y = bid & 63;
  const int xi = threadIdx.x >> 6;  // wave id: x-strip
  const int cl = threadIdx.x & 63;  // 2-channel group within half
  const int c0 = chalf * 128 + cl * 2;
  for (int i = threadIdx.x; i < 3456; i += 256) sw[i] = g_wperc[chalf * 3456 + i];
  for (int i = threadIdx.x; i < 384; i += 256) sb[i] = g_bperc[chalf * 384 + i];
  const int fp32 = g_flag;
  __syncthreads();
  float w[2][27], bias[2][3];
#pragma unroll
  for (int ch = 0; ch < 2; ++ch) {
    const int lc = cl * 2 + ch;  // local channel within half
#pragma unroll
    for (int t = 0; t < 3; ++t) {
      bias[ch][t] = b2f(sb[3 * lc + t]);
#pragma unroll
      for (int j = 0; j < 9; ++j)
        w[ch][t * 9 + j] = b2f(sw[(3 * lc + t) * 9 + j]);
    }
  }
  float hv[3][3][2];  // [row][colslot][ch]
  auto loadcol = [&](int xx, int cc) {
#pragma unroll
    for (int r = 0; r < 3; ++r) {
      const int yy = y - 1 + r;
      const bool ok = ((unsigned)yy < 64u) && ((unsigned)xx < 64u);
      if (ok) {
        const size_t idx = (((size_t)(b * 64 + yy) * 64) + xx) * 256 + c0;
        if (fp32) {
          const float2 v = *(const float2*)((const float*)hin + idx);
          hv[r][cc][0] = v.x;
          hv[r][cc][1] = v.y;
        } else {
          const unsigned v = *(const unsigned*)((const u16*)hin + idx);
          hv[r][cc][0] = b2f((u16)(v & 0xFFFF));
          hv[r][cc][1] = b2f((u16)(v >> 16));
        }
      } else {
        hv[r][cc][0] = 0.0f;
        hv[r][cc][1] = 0.0f;
      }
    }
  };
  const int x0 = xi * 16;
  loadcol(x0 - 1, 0);
  loadcol(x0, 1);
#pragma unroll
  for (int k = 0; k < 16; ++k) {
    const int x = x0 + k;
    loadcol(x + 1, (k + 2) % 3);
    const int cL = k % 3, cM = (k + 1) % 3, cR = (k + 2) % 3;
    const size_t pix = (size_t)(b * 64 + y) * 64 + x;
    // canonical bf16 h (center; exact round-trip for bf16 inputs)
    *(unsigned*)&g_h[pix * 256 + c0] =
        (unsigned)f2b(hv[1][cM][0]) | ((unsigned)f2b(hv[1][cM][1]) << 16);
    u16* op = &g_perc[pix * 768 + 3 * c0];  // lane stride 6 u16 = 12 B
    unsigned pk[3];
#pragma unroll
    for (int ch = 0; ch < 2; ++ch) {
#pragma unroll
      for (int t = 0; t < 3; ++t) {
        const float* wt = &w[ch][t * 9];
        float a = bias[ch][t];
        a += hv[0][cL][ch] * wt[0] + hv[0][cM][ch] * wt[1] + hv[0][cR][ch] * wt[2];
        a += hv[1][cL][ch] * wt[3] + hv[1][cM][ch] * wt[4] + hv[1][cR][ch] * wt[5];
        a += hv[2][cL][ch] * wt[6] + hv[2][cM][ch] * wt[7] + hv[2][cR][ch] * wt[8];
        const int o = 3 * ch + t;
        const unsigned bb = f2b(a);
        if (o & 1) pk[o >> 1] |= bb << 16; else pk[o >> 1] = bb;
      }
    }
    *(unsigned*)(op) = pk[0];      // 12 B per lane as 3 dword stores
    *(unsigned*)(op + 2) = pk[1];  // (4-aligned; 8-alignment not guaranteed)
    *(unsigned*)(op + 4) = pk[2];
  }
}

// --------------------------------------------------------------------------
// MFMA bf16 GEMM: C[M,N] = epi(A[M,K] * W[N,K]^T + bias[N])
// BM=BN=128, BK=64 (12/8/4 iters), 4 waves 2x2, 4x4 mfma_f32_16x16x32_bf16.
// global_load_lds(16B) staging into XOR-swizzled LDS: 16B slot s holds
// global chunk ((s>>3), (s&7)^((s>>3)&7)) -> ds_read_b128 aliasing is 2-way
// (free, m136). XCD swizzle: bid&7 picks M-slab (A shared within an XCD L2).
// MODE 0: perceived@wup1 +GELU -> hid.  MODE 1: hid@wup2 +h -> hnew.
// MODE 2: hnew@wqkv -> qkv (g_perc reuse).
// --------------------------------------------------------------------------
template <int MODE, int NB>
__global__ __launch_bounds__(256) void gemm_bt(int K) {
  const u16 *A, *Bw, *bias, *resid;
  u16* C;
  if (MODE == 0) { A = g_perc; Bw = g_wup1; bias = g_bup1; resid = nullptr; C = g_hid; }
  if (MODE == 1) { A = g_hid;  Bw = g_wup2; bias = g_bup2; resid = g_h;     C = g_hnew; }
  if (MODE == 2) { A = g_hnew; Bw = g_wqkv; bias = g_bqkv; resid = nullptr; C = g_perc; }
  const int N = NB * 128;

  __shared__ __align__(16) u16 Al[128 * 64];
  __shared__ __align__(16) u16 Bl[128 * 64];
  const int tid = threadIdx.x;
  const int wave = tid >> 6, lane = tid & 63;
  const int ln = lane & 15, quad = lane >> 4;
  const int lnx = ln & 7;
  const int mb_per_xcd = (gridDim.x / NB) >> 3;
  const int m_blk = (blockIdx.x & 7) * mb_per_xcd + (blockIdx.x >> 3) / NB;
  const int n_blk = (blockIdx.x >> 3) % NB;
  const int m0 = m_blk * 128, n0 = n_blk * 128;
  const int wm = (wave >> 1) * 64, wn = (wave & 1) * 64;
  floatx4 acc[4][4] = {};

  // staging geometry: 1024 slots of 16B per matrix; 4 rounds of 256.
  int srow[4], scol[4];
#pragma unroll
  for (int r = 0; r < 4; ++r) {
    const int slot = r * 256 + tid;
    srow[r] = slot >> 3;
    scol[r] = ((slot & 7) ^ (srow[r] & 7)) * 8;
  }

  for (int k0 = 0; k0 < K; k0 += 64) {
#pragma unroll
    for (int r = 0; r < 4; ++r)
      gload16(&A[(size_t)(m0 + srow[r]) * K + k0 + scol[r]],
              &Al[(r * 256 + tid) * 8]);
#pragma unroll
    for (int r = 0; r < 4; ++r)
      gload16(&Bw[(size_t)(n0 + srow[r]) * K + k0 + scol[r]],
              &Bl[(r * 256 + tid) * 8]);
    __syncthreads();
#pragma unroll
    for (int kk8 = 0; kk8 < 8; kk8 += 4) {
      bf16x8 af[4], bfr[4];
#pragma unroll
      for (int i = 0; i < 4; ++i) {
        const int row = wm + i * 16 + ln;
        af[i] = *(const bf16x8*)(&Al[(row * 8 + ((kk8 + quad) ^ lnx)) * 8]);
      }
#pragma unroll
      for (int j = 0; j < 4; ++j) {
        const int row = wn + j * 16 + ln;
        bfr[j] = *(const bf16x8*)(&Bl[(row * 8 + ((kk8 + quad) ^ lnx)) * 8]);
      }
#pragma unroll
      for (int i = 0; i < 4; ++i)
#pragma unroll
        for (int j = 0; j < 4; ++j)
          acc[i][j] = __builtin_amdgcn_mfma_f32_16x16x32_bf16(af[i], bfr[j],
                                                              acc[i][j], 0, 0, 0);
    }
    __syncthreads();
  }

#pragma unroll
  for (int i = 0; i < 4; ++i) {
#pragma unroll
    for (int rr = 0; rr < 4; ++rr) {
      const int m = m0 + wm + i * 16 + quad * 4 + rr;
#pragma unroll
      for (int j = 0; j < 4; ++j) {
        const int n = n0 + wn + j * 16 + ln;
        float v = acc[i][j][rr] + b2f(bias[n]);
        if (MODE == 0) v = 0.5f * v * (1.0f + erff(v * 0.70710678118654752f));
        if (MODE == 1) v += b2f(resid[(size_t)m * N + n]);
        C[(size_t)m * N + n] = f2b(v);
      }
    }
  }
}

// --------------------------------------------------------------------------
// 3x3 windowed local attention (zero-padded borders). Wave = 2 pixels
// (32 lanes each), lane = 8 channels (uint4 loads). OOB neighbor => score 0
// in softmax, zero value. out = hnew + attn, dtype per g_flag.
// --------------------------------------------------------------------------
__global__ __launch_bounds__(256) void attn_kernel(void* __restrict__ outv) {
  const int wv = threadIdx.x >> 6, lane = threadIdx.x & 63;
  const int half = lane >> 5, cl = lane & 31;
  const int c0 = cl * 8;
  const int pix = blockIdx.x * 8 + wv * 2 + half;
  const int y = (pix >> 6) & 63, x = pix & 63;
  float q[8];
  ld8(g_perc + (size_t)pix * 768 + c0, q);
  float s[9];
  int nidx[9];
#pragma unroll
  for (int j = 0; j < 9; ++j) {
    const int dy = j / 3 - 1, dx = j % 3 - 1;
    const int yy = y + dy, xx = x + dx;
    const bool ok = ((unsigned)yy < 64u) && ((unsigned)xx < 64u);
    const int np = pix + dy * 64 + dx;  // same image when ok
    nidx[j] = ok ? np : -1;
    float p = 0.0f;
    if (ok) {
      float kv[8];
      ld8(g_perc + (size_t)np * 768 + 256 + c0, kv);
      p = q[0] * kv[0] + q[1] * kv[1] + q[2] * kv[2] + q[3] * kv[3] +
          q[4] * kv[4] + q[5] * kv[5] + q[6] * kv[6] + q[7] * kv[7];
    }
#pragma unroll
    for (int off = 16; off >= 1; off >>= 1) p += __shfl_xor(p, off, 64);
    s[j] = p * 0.0625f;  // 1/sqrt(256)
  }
  float mx = s[0];
#pragma unroll
  for (int j = 1; j < 9; ++j) mx = fmaxf(mx, s[j]);
  float e[9], den = 0.0f;
#pragma unroll
  for (int j = 0; j < 9; ++j) {
    e[j] = expf(s[j] - mx);
    den += e[j];
  }
  const float inv = 1.0f / den;
  float a[8];
  ld8(g_hnew + (size_t)pix * 256 + c0, a);
#pragma unroll
  for (int j = 0; j < 9; ++j) {
    if (nidx[j] >= 0) {
      const float wgt = e[j] * inv;
      float vv[8];
      ld8(g_perc + (size_t)nidx[j] * 768 + 512 + c0, vv);
#pragma unroll
      for (int t = 0; t < 8; ++t) a[t] += wgt * vv[t];
    }
  }
  const size_t o = (size_t)pix * 256 + c0;
  if (g_flag) {
    float4 r0 = {a[0], a[1], a[2], a[3]};
    float4 r1 = {a[4], a[5], a[6], a[7]};
    *(float4*)((float*)outv + o) = r0;
    *(float4*)((float*)outv + o + 4) = r1;
  } else {
    uint4 r;
    r.x = (unsigned)f2b(a[0]) | ((unsigned)f2b(a[1]) << 16);
    r.y = (unsigned)f2b(a[2]) | ((unsigned)f2b(a[3]) << 16);
    r.z = (unsigned)f2b(a[4]) | ((unsigned)f2b(a[5]) << 16);
    r.w = (unsigned)f2b(a[6]) | ((unsigned)f2b(a[7]) << 16);
    *(uint4*)((u16*)outv + o) = r;
  }
}

// --------------------------------------------------------------------------
extern "C" void kernel_launch(void* const* d_in, const int* in_sizes, int n_in,
                              void* d_out, int d_out_size, void* d_ws,
                              size_t ws_size, hipStream_t stream) {
  (void)d_ws; (void)ws_size;
  probe_kernel<<<1, 256, 0, stream>>>((const u16*)d_in[0]);
  conv_w_kernel<<<360, 256, 0, stream>>>(d_in[1], d_in[2], d_in[3], d_in[4],
                                         d_in[5], d_in[6], d_in[7], d_in[8]);
  // perception + h canonicalization (2048 blocks: (b,y) x channel-half)
  perc_kernel<<<2048, 256, 0, stream>>>(d_in[0]);
  // hid = GELU(perceived @ w_up1^T + b_up1)   [65536 x 512, K=768]
  gemm_bt<0, 4><<<2048, 256, 0, stream>>>(768);
  // h_new = h + hid @ w_up2^T + b_up2         [65536 x 256, K=512]
  gemm_bt<1, 2><<<1024, 256, 0, stream>>>(512);
  // qkv = h_new @ w_qkv^T + b_qkv             [65536 x 768, K=256]
  gemm_bt<2, 6><<<3072, 256, 0, stream>>>(256);
  // out = h_new + local_attn(qkv)
  attn_kernel<<<8192, 256, 0, stream>>>(d_out);
}